// Round 1
// baseline (335.378 us; speedup 1.0000x reference)
//
#include <hip/hip_runtime.h>
#include <cmath>

// MoE router: logits = x[T,H] @ w[E,H]^T (fp32), sigmoid, top-8 on (prob+bias),
// weights = topk_prob / sum * 2.5. Outputs: weights[T,8] f32, indices[T,8] as f32.
//
// Kernel A: fp32 vector GEMM, 32 tokens x 64 experts per block, H-split across
// blockIdx.y into d_ws partials (deterministic combine in kernel B).
// Kernel B: one wave per token, butterfly argmax top-8 with lower-index tie-break.

#define E_DIM 64
#define TB 32
#define HC 64

__global__ __launch_bounds__(256) void router_gemm(
    const float* __restrict__ x, const float* __restrict__ w,
    float* __restrict__ part, int T, int Hdim, int hPerPart)
{
  __shared__ __align__(16) float xs[TB * HC];     // [t][h^((t>>2)*4)] swizzled
  __shared__ __align__(16) float wsm[E_DIM * HC]; // [e][h^(((e>>1)&7)*4)] swizzled

  const int tid = threadIdx.x;
  const int tg = tid & 7;   // token group: tokens tg*4 .. tg*4+3
  const int eg = tid >> 3;  // expert group: experts eg*2, eg*2+1
  const int t0 = blockIdx.x * TB;
  const int hbase = blockIdx.y * hPerPart;

  float acc[4][2];
#pragma unroll
  for (int r = 0; r < 4; ++r) { acc[r][0] = 0.f; acc[r][1] = 0.f; }

  const int nChunks = hPerPart / HC;
  for (int ch = 0; ch < nChunks; ++ch) {
    const int hb = hbase + ch * HC;

    // global -> regs (coalesced float4)
    float4 xr[2];
#pragma unroll
    for (int rep = 0; rep < 2; ++rep) {
      int ci = rep * 256 + tid;
      int t = ci >> 4, j = ci & 15;
      xr[rep] = *(const float4*)(x + (size_t)(t0 + t) * Hdim + hb + j * 4);
    }
    float4 wr[4];
#pragma unroll
    for (int rep = 0; rep < 4; ++rep) {
      int ci = rep * 256 + tid;
      int e = ci >> 4, j = ci & 15;
      wr[rep] = *(const float4*)(w + (size_t)e * Hdim + hb + j * 4);
    }

    __syncthreads();  // previous iter's LDS reads done

    // regs -> LDS with XOR swizzle (breaks 8-way bank conflict on reads)
#pragma unroll
    for (int rep = 0; rep < 2; ++rep) {
      int ci = rep * 256 + tid;
      int t = ci >> 4, j = ci & 15;
      *(float4*)(xs + t * HC + ((j * 4) ^ ((t >> 2) * 4))) = xr[rep];
    }
#pragma unroll
    for (int rep = 0; rep < 4; ++rep) {
      int ci = rep * 256 + tid;
      int e = ci >> 4, j = ci & 15;
      *(float4*)(wsm + e * HC + ((j * 4) ^ (((e >> 1) & 7) * 4))) = wr[rep];
    }

    __syncthreads();  // LDS writes visible

    const int xsw = tg * 4;
    const int wswz = (eg & 7) * 4;
#pragma unroll
    for (int hq = 0; hq < HC; hq += 4) {
      float4 xv[4], wv[2];
#pragma unroll
      for (int r = 0; r < 4; ++r)
        xv[r] = *(const float4*)(xs + (tg * 4 + r) * HC + (hq ^ xsw));
#pragma unroll
      for (int c = 0; c < 2; ++c)
        wv[c] = *(const float4*)(wsm + (eg * 2 + c) * HC + (hq ^ wswz));
#pragma unroll
      for (int r = 0; r < 4; ++r)
#pragma unroll
        for (int c = 0; c < 2; ++c) {
          acc[r][c] = fmaf(xv[r].x, wv[c].x, acc[r][c]);
          acc[r][c] = fmaf(xv[r].y, wv[c].y, acc[r][c]);
          acc[r][c] = fmaf(xv[r].z, wv[c].z, acc[r][c]);
          acc[r][c] = fmaf(xv[r].w, wv[c].w, acc[r][c]);
        }
    }
  }

  // raw partial logits -> ws[part][T][64]
#pragma unroll
  for (int r = 0; r < 4; ++r) {
    int trow = t0 + tg * 4 + r;
    size_t base = ((size_t)blockIdx.y * T + trow) * E_DIM + eg * 2;
    *(float2*)(part + base) = make_float2(acc[r][0], acc[r][1]);
  }
}

__global__ __launch_bounds__(256) void router_topk(
    const float* __restrict__ part, const float* __restrict__ bias,
    float* __restrict__ outw, float* __restrict__ outi, int T, int nparts)
{
  const int lane = threadIdx.x & 63;
  const int t = blockIdx.x * 4 + (threadIdx.x >> 6);
  if (t >= T) return;

  float logit = 0.f;
  for (int p = 0; p < nparts; ++p)
    logit += part[((size_t)p * T + t) * E_DIM + lane];

  const float prob = 1.0f / (1.0f + expf(-logit));
  float v = prob + bias[lane];  // ranking key (biased); weights use unbiased prob

  float sum = 0.f;
  float selw = 0.f;
  int   seli = 0;

#pragma unroll
  for (int k = 0; k < 8; ++k) {
    float rv = v;
    int   ri = lane;
#pragma unroll
    for (int off = 32; off > 0; off >>= 1) {
      float ov = __shfl_xor(rv, off);
      int   oi = __shfl_xor(ri, off);
      // descending value; ties -> lower index (matches jax.lax.top_k)
      if (ov > rv || (ov == rv && oi < ri)) { rv = ov; ri = oi; }
    }
    float pwin = __shfl(prob, ri);  // unbiased prob of winner (lane == expert)
    sum += pwin;
    if (lane == k)  { selw = pwin; seli = ri; }
    if (lane == ri) v = -INFINITY;  // mask winner
  }

  if (lane < 8) {
    float scale = 2.5f / (sum + 1e-20f);
    outw[(size_t)t * 8 + lane] = selw * scale;
    outi[(size_t)t * 8 + lane] = (float)seli;  // indices as float values
  }
}

extern "C" void kernel_launch(void* const* d_in, const int* in_sizes, int n_in,
                              void* d_out, int out_size, void* d_ws, size_t ws_size,
                              hipStream_t stream) {
  const float* x    = (const float*)d_in[0];
  const float* w    = (const float*)d_in[1];
  const float* bias = (const float*)d_in[2];

  const int E    = in_sizes[2];           // 64
  const int Hdim = in_sizes[1] / E;       // 4096
  const int T    = in_sizes[0] / Hdim;    // 16384

  float* part = (float*)d_ws;
  const size_t need2 = (size_t)2 * T * E_DIM * sizeof(float);
  const int nparts = (ws_size >= need2) ? 2 : 1;
  const int hPerPart = Hdim / nparts;

  dim3 gridA(T / TB, nparts);
  router_gemm<<<gridA, 256, 0, stream>>>(x, w, part, T, Hdim, hPerPart);

  float* outw = (float*)d_out;
  float* outi = outw + (size_t)T * 8;
  dim3 gridB((T + 3) / 4);
  router_topk<<<gridB, 256, 0, stream>>>(part, bias, outw, outi, T, nparts);
}

// Round 3
// 130.479 us; speedup vs baseline: 2.5703x; 2.5703x over previous
//
#include <hip/hip_runtime.h>
#include <cmath>

// MoE router via 3-way bf16-split MFMA emulation of fp32 GEMM, with
// COMPENSATED accumulation (TwoSum) to keep logit error ~1e-7 (near-tie
// index flips vs the fp32 numpy reference killed the uncompensated version).
//
// logits[T,64] = x[T,4096] @ w[64,4096]^T, sigmoid, top-8 on prob+bias,
// weights = p/sum*2.5. Outputs: weights[T,8] f32, then indices[T,8] as f32.
//
// x = xh+xm+xl (bf16), w = wh+wm+wl. 6 MFMAs: hH->acc_m; hM,mH,hL,mM,lH->acc_c.
// acc_m folded into (sum,comp) TwoSum pair every 2 chunks (short fp32 chains).

typedef float f32x4 __attribute__((ext_vector_type(4)));
typedef short s16x8 __attribute__((ext_vector_type(8)));

#define E_DIM 64
#define KC 64
#define CH_BYTES 24576   // 3 splits * 64 e * 64 k * 2B
#define STILE 8192       // one split tile: 64 e * 128 B

__device__ __forceinline__ unsigned short f2bf(float f) {
  unsigned u = __float_as_uint(f);
  u += 0x7fffu + ((u >> 16) & 1u);   // round-to-nearest-even
  return (unsigned short)(u >> 16);
}
__device__ __forceinline__ float bf2f(unsigned short s) {
  return __uint_as_float(((unsigned)s) << 16);
}

// ---- kernel W: split gate weight into 3 bf16 planes, pre-swizzled ----
__global__ __launch_bounds__(256) void split_w(
    const float* __restrict__ w, unsigned char* __restrict__ w3, int Hdim)
{
  const int kpr = Hdim >> 4;                      // 16-elem groups per row
  const int g = blockIdx.x * 256 + threadIdx.x;   // E*Hdim/16 total
  const int e = g / kpr;
  const int k0 = (g - e * kpr) * 16;
  if (e >= E_DIM) return;

  const float* src = w + (size_t)e * Hdim + k0;
  float f[16];
#pragma unroll
  for (int i = 0; i < 4; ++i) {
    float4 v = *(const float4*)(src + i * 4);
    f[i*4+0] = v.x; f[i*4+1] = v.y; f[i*4+2] = v.z; f[i*4+3] = v.w;
  }
  unsigned short hs[16], ms[16], ls[16];
#pragma unroll
  for (int i = 0; i < 16; ++i) {
    unsigned short h = f2bf(f[i]);
    float r1 = f[i] - bf2f(h);
    unsigned short m = f2bf(r1);
    float r2 = r1 - bf2f(m);
    hs[i] = h; ms[i] = m; ls[i] = f2bf(r2);
  }
  const int c   = k0 >> 6;              // chunk of 64 k
  const int klb = (k0 & 63) * 2;        // byte offset within 128B row
  const int swz = (e & 7) << 4;
  unsigned char* base = w3 + (size_t)c * CH_BYTES + (size_t)e * 128;

#define STORE_SPLIT(arr, s)                                             \
  do {                                                                  \
    _Pragma("unroll")                                                   \
    for (int h2 = 0; h2 < 2; ++h2) {                                    \
      s16x8 pack;                                                       \
      _Pragma("unroll")                                                 \
      for (int j = 0; j < 8; ++j) pack[j] = (short)arr[h2*8 + j];       \
      *(s16x8*)(base + (s)*STILE + ((klb + h2*16) ^ swz)) = pack;       \
    }                                                                   \
  } while (0)

  STORE_SPLIT(hs, 0);
  STORE_SPLIT(ms, 1);
  STORE_SPLIT(ls, 2);
#undef STORE_SPLIT
}

// ---- kernel G: MFMA GEMM (compensated) + fused sigmoid/top-k ----
__global__ __launch_bounds__(256) void router_mfma(
    const float* __restrict__ x, const unsigned char* __restrict__ w3,
    const float* __restrict__ bias, float* __restrict__ outw,
    float* __restrict__ outi, int T, int Hdim)
{
  __shared__ __align__(16) unsigned char lds[2][CH_BYTES];  // 48 KB

  const int tid  = threadIdx.x;
  const int wid  = tid >> 6;
  const int lane = tid & 63;
  const int lc   = lane & 15;   // A: token row / B: expert col / D: col
  const int lq   = lane >> 4;   // k-quadrant / D row group
  const int t0   = blockIdx.x * 64;

  const float* xp = x + (size_t)(t0 + wid * 16 + lc) * Hdim + lq * 8;

  f32x4 acc_m[4] = {{0,0,0,0},{0,0,0,0},{0,0,0,0},{0,0,0,0}};  // hH, short chains
  f32x4 acc_c[4] = {{0,0,0,0},{0,0,0,0},{0,0,0,0},{0,0,0,0}};  // corrections
  f32x4 sum_[4]  = {{0,0,0,0},{0,0,0,0},{0,0,0,0},{0,0,0,0}};  // TwoSum main
  f32x4 comp[4]  = {{0,0,0,0},{0,0,0,0},{0,0,0,0},{0,0,0,0}};  // TwoSum comp

  const int swz  = (lc & 7) << 4;
  const int kb0  = (0  + lq * 16) ^ swz;   // ks=0 in-row byte (swizzled)
  const int kb1  = (64 + lq * 16) ^ swz;   // ks=1
  const int erow = lc * 128;

#define STAGE(c, b)                                                          \
  do {                                                                       \
    const unsigned char* gs = w3 + (size_t)(c) * CH_BYTES + tid * 16;        \
    unsigned char* ld_ = &lds[b][0] + tid * 16;                              \
    _Pragma("unroll")                                                        \
    for (int i = 0; i < 6; ++i)                                              \
      __builtin_amdgcn_global_load_lds(                                      \
          (const __attribute__((address_space(1))) unsigned int*)(gs + i*4096), \
          (__attribute__((address_space(3))) unsigned int*)(ld_ + i*4096),   \
          16, 0, 0);                                                         \
  } while (0)

#define LOADX(c, xr)                                                         \
  do {                                                                       \
    const float* p_ = xp + (size_t)(c) * KC;                                 \
    xr[0] = *(const float4*)(p_);                                            \
    xr[1] = *(const float4*)(p_ + 4);                                        \
    xr[2] = *(const float4*)(p_ + 32);                                       \
    xr[3] = *(const float4*)(p_ + 36);                                       \
  } while (0)

#define COMPUTE(xr, b)                                                       \
  do {                                                                       \
    _Pragma("unroll")                                                        \
    for (int ks = 0; ks < 2; ++ks) {                                         \
      float fv[8] = {xr[ks*2].x,   xr[ks*2].y,   xr[ks*2].z,   xr[ks*2].w,   \
                     xr[ks*2+1].x, xr[ks*2+1].y, xr[ks*2+1].z, xr[ks*2+1].w};\
      s16x8 ah, am, al;                                                      \
      _Pragma("unroll")                                                      \
      for (int j = 0; j < 8; ++j) {                                          \
        unsigned short h_ = f2bf(fv[j]);                                     \
        float r1_ = fv[j] - bf2f(h_);                                        \
        unsigned short m_ = f2bf(r1_);                                       \
        float r2_ = r1_ - bf2f(m_);                                          \
        ah[j] = (short)h_; am[j] = (short)m_; al[j] = (short)f2bf(r2_);      \
      }                                                                      \
      const unsigned char* B_ = &lds[b][0];                                  \
      const int kb_ = ks ? kb1 : kb0;                                        \
      _Pragma("unroll")                                                      \
      for (int n = 0; n < 4; ++n) {                                          \
        const int ro_ = n * 2048 + erow + kb_;                               \
        s16x8 bh = *(const s16x8*)(B_ + ro_);                                \
        s16x8 bm = *(const s16x8*)(B_ + STILE + ro_);                        \
        s16x8 bl = *(const s16x8*)(B_ + 2*STILE + ro_);                      \
        acc_m[n] = __builtin_amdgcn_mfma_f32_16x16x32_bf16(ah, bh, acc_m[n], 0,0,0); \
        acc_c[n] = __builtin_amdgcn_mfma_f32_16x16x32_bf16(ah, bm, acc_c[n], 0,0,0); \
        acc_c[n] = __builtin_amdgcn_mfma_f32_16x16x32_bf16(am, bh, acc_c[n], 0,0,0); \
        acc_c[n] = __builtin_amdgcn_mfma_f32_16x16x32_bf16(ah, bl, acc_c[n], 0,0,0); \
        acc_c[n] = __builtin_amdgcn_mfma_f32_16x16x32_bf16(am, bm, acc_c[n], 0,0,0); \
        acc_c[n] = __builtin_amdgcn_mfma_f32_16x16x32_bf16(al, bh, acc_c[n], 0,0,0); \
      }                                                                      \
    }                                                                        \
  } while (0)

  // TwoSum fold: (sum_,comp) += acc_m  exactly; acc_m reset to 0.
  // Adds/subs only -> immune to ffp-contract; no fast-math flags used.
#define FOLD()                                                               \
  do {                                                                       \
    _Pragma("unroll")                                                        \
    for (int n = 0; n < 4; ++n) {                                            \
      _Pragma("unroll")                                                      \
      for (int r = 0; r < 4; ++r) {                                          \
        float a_ = acc_m[n][r];                                              \
        float s_ = sum_[n][r];                                               \
        float t_ = s_ + a_;                                                  \
        float z_ = t_ - s_;                                                  \
        comp[n][r] += (s_ - (t_ - z_)) + (a_ - z_);                          \
        sum_[n][r] = t_;                                                     \
        acc_m[n][r] = 0.f;                                                   \
      }                                                                      \
    }                                                                        \
  } while (0)

  const int nch = Hdim / KC;   // 64
  float4 xa[4], xb[4];

  STAGE(0, 0);
  LOADX(0, xa);
  __syncthreads();

#pragma unroll 1
  for (int c2 = 0; c2 < nch / 2; ++c2) {
    const int c = c2 * 2;
    STAGE(c + 1, 1);
    LOADX(c + 1, xb);
    COMPUTE(xa, 0);
    __syncthreads();
    if (c + 2 < nch) { STAGE(c + 2, 0); LOADX(c + 2, xa); }
    COMPUTE(xb, 1);
    __syncthreads();
    FOLD();   // 4 hH MFMAs per fold group -> short fp32 chains
  }

  // ---- fused epilogue: sigmoid + bias, top-8 per token ----
  // logit(token t0+wid*16+lq*4+r, expert n*16+lc)
  float bias_v[4];
#pragma unroll
  for (int n = 0; n < 4; ++n) bias_v[n] = bias[n * 16 + lc];

  float pr[4][4], bi[4][4];
#pragma unroll
  for (int n = 0; n < 4; ++n)
#pragma unroll
    for (int r = 0; r < 4; ++r) {
      float logit = sum_[n][r] + (comp[n][r] + acc_c[n][r]);
      float p = 1.0f / (1.0f + expf(-logit));
      pr[n][r] = p;
      bi[n][r] = p + bias_v[n];
    }

#pragma unroll
  for (int r = 0; r < 4; ++r) {
    float v0 = bi[0][r], v1 = bi[1][r], v2 = bi[2][r], v3 = bi[3][r];
    float p0 = pr[0][r], p1 = pr[1][r], p2 = pr[2][r], p3 = pr[3][r];
    float sum = 0.f, selp = 0.f;
    int seli = 0;
#pragma unroll
    for (int k = 0; k < 8; ++k) {
      // lane-local best of 4 (ascending n == ascending expert idx -> strict >)
      float bv = v0; int bn = 0; float bp = p0;
      if (v1 > bv) { bv = v1; bn = 1; bp = p1; }
      if (v2 > bv) { bv = v2; bn = 2; bp = p2; }
      if (v3 > bv) { bv = v3; bn = 3; bp = p3; }
      int be = bn * 16 + lc;
      // butterfly across the 16-lane group (token fixed by lq group)
#pragma unroll
      for (int off = 8; off >= 1; off >>= 1) {
        float ov = __shfl_xor(bv, off);
        float op = __shfl_xor(bp, off);
        int   oe = __shfl_xor(be, off);
        if (ov > bv || (ov == bv && oe < be)) { bv = ov; bp = op; be = oe; }
      }
      sum += bp;
      if (lc == k) { selp = bp; seli = be; }
      if (lc == (be & 15)) {  // mask winner (this lane owns its column)
        int gsel = be >> 4;
        if      (gsel == 0) v0 = -1e30f;
        else if (gsel == 1) v1 = -1e30f;
        else if (gsel == 2) v2 = -1e30f;
        else                v3 = -1e30f;
      }
    }
    if (lc < 8) {
      const int t = t0 + wid * 16 + lq * 4 + r;
      outw[(size_t)t * 8 + lc] = selp * 2.5f / (sum + 1e-20f);
      outi[(size_t)t * 8 + lc] = (float)seli;
    }
  }
}

extern "C" void kernel_launch(void* const* d_in, const int* in_sizes, int n_in,
                              void* d_out, int out_size, void* d_ws, size_t ws_size,
                              hipStream_t stream) {
  const float* x    = (const float*)d_in[0];
  const float* w    = (const float*)d_in[1];
  const float* bias = (const float*)d_in[2];

  const int E    = in_sizes[2];          // 64
  const int Hdim = in_sizes[1] / E;      // 4096
  const int T    = in_sizes[0] / Hdim;   // 16384

  unsigned char* w3 = (unsigned char*)d_ws;   // 1.5 MB

  const int nElemGroups = E * Hdim / 16;
  split_w<<<(nElemGroups + 255) / 256, 256, 0, stream>>>(w, w3, Hdim);

  float* outw = (float*)d_out;
  float* outi = outw + (size_t)T * 8;
  router_mfma<<<T / 64, 256, 0, stream>>>(x, w3, bias, outw, outi, T, Hdim);
}

// Round 4
// 114.588 us; speedup vs baseline: 2.9268x; 1.1387x over previous
//
#include <hip/hip_runtime.h>
#include <cmath>

// MoE router via 3-way bf16-split MFMA emulation of fp32 GEMM, compensated
// (TwoSum) accumulation. R4: 4-way K-split for occupancy (R3 was 1 block/CU,
// 11% occupancy, pure latency-bound). Partials stored as (hi,lo) f32 pairs to
// preserve R3's exact-fold precision; combined in the top-k kernel by TwoSum.
//
// logits[T,64] = x[T,4096] @ w[64,4096]^T, sigmoid, top-8 on prob+bias,
// weights = p/sum*2.5. Outputs: weights[T,8] f32, then indices[T,8] as f32.
//
// x = xh+xm+xl (bf16), w = wh+wm+wl. 6 MFMAs: hH->acc_m; rest->acc_c.
// LDS: KC=32 chunks (12KB), double-buffered = 24KB -> 4 blocks/CU at grid
// (T/64)x4 = 1024 blocks, 16 waves/CU. Swizzle: 64B rows, 16B slot XOR
// ((e>>1)&3)<<4 -> 2-way per 16-lane phase (free).

typedef float f32x4 __attribute__((ext_vector_type(4)));
typedef short s16x8 __attribute__((ext_vector_type(8)));

#define E_DIM 64
#define KC 32
#define CH_BYTES 12288   // 3 splits * 64 e * 32 k * 2B
#define STILE 4096       // one split tile: 64 e * 64 B
#define NPART 4
#define W3_OFF 0
#define HI_OFF (2u << 20)   // 2 MB (w3 is 1.5 MB)

__device__ __forceinline__ unsigned short f2bf(float f) {
  unsigned u = __float_as_uint(f);
  u += 0x7fffu + ((u >> 16) & 1u);   // round-to-nearest-even
  return (unsigned short)(u >> 16);
}
__device__ __forceinline__ float bf2f(unsigned short s) {
  return __uint_as_float(((unsigned)s) << 16);
}

// ---- kernel W: split gate weight into 3 bf16 planes, pre-swizzled ----
__global__ __launch_bounds__(256) void split_w(
    const float* __restrict__ w, unsigned char* __restrict__ w3, int Hdim)
{
  const int kpr = Hdim >> 4;                      // 16-elem groups per row
  const int g = blockIdx.x * 256 + threadIdx.x;
  const int e = g / kpr;
  const int k0 = (g - e * kpr) * 16;
  if (e >= E_DIM) return;

  const float* src = w + (size_t)e * Hdim + k0;
  float f[16];
#pragma unroll
  for (int i = 0; i < 4; ++i) {
    float4 v = *(const float4*)(src + i * 4);
    f[i*4+0] = v.x; f[i*4+1] = v.y; f[i*4+2] = v.z; f[i*4+3] = v.w;
  }
  unsigned short hs[16], ms[16], ls[16];
#pragma unroll
  for (int i = 0; i < 16; ++i) {
    unsigned short h = f2bf(f[i]);
    float r1 = f[i] - bf2f(h);
    unsigned short m = f2bf(r1);
    float r2 = r1 - bf2f(m);
    hs[i] = h; ms[i] = m; ls[i] = f2bf(r2);
  }
  const int c   = k0 >> 5;              // chunk of 32 k
  const int klb = (k0 & 31) * 2;        // byte offset within 64B row
  const int swz = ((e >> 1) & 3) << 4;
  unsigned char* base = w3 + (size_t)c * CH_BYTES + (size_t)e * 64;

#define STORE_SPLIT(arr, s)                                             \
  do {                                                                  \
    _Pragma("unroll")                                                   \
    for (int h2 = 0; h2 < 2; ++h2) {                                    \
      s16x8 pack;                                                       \
      _Pragma("unroll")                                                 \
      for (int j = 0; j < 8; ++j) pack[j] = (short)arr[h2*8 + j];       \
      *(s16x8*)(base + (s)*STILE + ((klb + h2*16) ^ swz)) = pack;       \
    }                                                                   \
  } while (0)

  STORE_SPLIT(hs, 0);
  STORE_SPLIT(ms, 1);
  STORE_SPLIT(ls, 2);
#undef STORE_SPLIT
}

// ---- kernel G: MFMA GEMM (compensated). gridDim.y==1 -> fused topk;
//      gridDim.y==NPART -> write (hi,lo) partials. ----
__global__ __launch_bounds__(256, 4) void router_mfma(
    const float* __restrict__ x, const unsigned char* __restrict__ w3,
    const float* __restrict__ bias, float* __restrict__ outw,
    float* __restrict__ outi, float* __restrict__ hi_p,
    float* __restrict__ lo_p, int T, int Hdim)
{
  __shared__ __align__(16) unsigned char lds[2][CH_BYTES];  // 24 KB

  const int tid  = threadIdx.x;
  const int wid  = tid >> 6;
  const int lane = tid & 63;
  const int lc   = lane & 15;   // A: token row / B: expert col / D: col
  const int lq   = lane >> 4;   // k-quadrant / D row group
  const int t0   = blockIdx.x * 64;
  const int by   = blockIdx.y;
  const int nch  = Hdim / KC / gridDim.y;   // chunks per block

  const unsigned char* w3p = w3 + (size_t)by * nch * CH_BYTES;
  const float* xp = x + (size_t)(t0 + wid * 16 + lc) * Hdim
                      + (size_t)by * nch * KC + lq * 8;

  f32x4 acc_m[4] = {{0,0,0,0},{0,0,0,0},{0,0,0,0},{0,0,0,0}};  // hH (short chains)
  f32x4 acc_c[4] = {{0,0,0,0},{0,0,0,0},{0,0,0,0},{0,0,0,0}};  // corrections
  f32x4 sum_[4]  = {{0,0,0,0},{0,0,0,0},{0,0,0,0},{0,0,0,0}};  // TwoSum main
  f32x4 comp[4]  = {{0,0,0,0},{0,0,0,0},{0,0,0,0},{0,0,0,0}};  // TwoSum comp

  const int kbyte = (lq * 16) ^ (((lc >> 1) & 3) << 4);  // swizzled slot
  const int erow  = lc * 64;

#define STAGE(c, b)                                                          \
  do {                                                                       \
    const unsigned char* gs = w3p + (size_t)(c) * CH_BYTES + tid * 16;       \
    unsigned char* ld_ = &lds[b][0] + tid * 16;                              \
    _Pragma("unroll")                                                        \
    for (int i = 0; i < 3; ++i)                                              \
      __builtin_amdgcn_global_load_lds(                                      \
          (const __attribute__((address_space(1))) unsigned int*)(gs + i*4096), \
          (__attribute__((address_space(3))) unsigned int*)(ld_ + i*4096),   \
          16, 0, 0);                                                         \
  } while (0)

#define LOADX(c, xr)                                                         \
  do {                                                                       \
    const float* p_ = xp + (size_t)(c) * KC;                                 \
    xr[0] = *(const float4*)(p_);                                            \
    xr[1] = *(const float4*)(p_ + 4);                                        \
  } while (0)

#define COMPUTE(xr, b)                                                       \
  do {                                                                       \
    float fv[8] = {xr[0].x, xr[0].y, xr[0].z, xr[0].w,                       \
                   xr[1].x, xr[1].y, xr[1].z, xr[1].w};                      \
    s16x8 ah, am, al;                                                        \
    _Pragma("unroll")                                                        \
    for (int j = 0; j < 8; ++j) {                                            \
      unsigned short h_ = f2bf(fv[j]);                                       \
      float r1_ = fv[j] - bf2f(h_);                                          \
      unsigned short m_ = f2bf(r1_);                                         \
      float r2_ = r1_ - bf2f(m_);                                            \
      ah[j] = (short)h_; am[j] = (short)m_; al[j] = (short)f2bf(r2_);        \
    }                                                                        \
    const unsigned char* B_ = &lds[b][0];                                    \
    _Pragma("unroll")                                                        \
    for (int n = 0; n < 4; ++n) {                                            \
      const int ro_ = n * 1024 + erow + kbyte;                               \
      s16x8 bh = *(const s16x8*)(B_ + ro_);                                  \
      s16x8 bm = *(const s16x8*)(B_ + STILE + ro_);                          \
      s16x8 bl = *(const s16x8*)(B_ + 2*STILE + ro_);                        \
      acc_m[n] = __builtin_amdgcn_mfma_f32_16x16x32_bf16(ah, bh, acc_m[n], 0,0,0); \
      acc_c[n] = __builtin_amdgcn_mfma_f32_16x16x32_bf16(ah, bm, acc_c[n], 0,0,0); \
      acc_c[n] = __builtin_amdgcn_mfma_f32_16x16x32_bf16(am, bh, acc_c[n], 0,0,0); \
      acc_c[n] = __builtin_amdgcn_mfma_f32_16x16x32_bf16(ah, bl, acc_c[n], 0,0,0); \
      acc_c[n] = __builtin_amdgcn_mfma_f32_16x16x32_bf16(am, bm, acc_c[n], 0,0,0); \
      acc_c[n] = __builtin_amdgcn_mfma_f32_16x16x32_bf16(al, bh, acc_c[n], 0,0,0); \
    }                                                                        \
  } while (0)

  // TwoSum fold: (sum_,comp) += acc_m exactly; acc_m reset. Adds/subs only.
#define FOLD()                                                               \
  do {                                                                       \
    _Pragma("unroll")                                                        \
    for (int n = 0; n < 4; ++n) {                                            \
      _Pragma("unroll")                                                      \
      for (int r = 0; r < 4; ++r) {                                          \
        float a_ = acc_m[n][r];                                              \
        float s_ = sum_[n][r];                                               \
        float t_ = s_ + a_;                                                  \
        float z_ = t_ - s_;                                                  \
        comp[n][r] += (s_ - (t_ - z_)) + (a_ - z_);                          \
        sum_[n][r] = t_;                                                     \
        acc_m[n][r] = 0.f;                                                   \
      }                                                                      \
    }                                                                        \
  } while (0)

  float4 xa[2], xb[2];

  STAGE(0, 0);
  LOADX(0, xa);
  __syncthreads();

#pragma unroll 1
  for (int c2 = 0; c2 < nch / 2; ++c2) {
    const int c = c2 * 2;
    STAGE(c + 1, 1);
    LOADX(c + 1, xb);
    COMPUTE(xa, 0);
    __syncthreads();
    if (c + 2 < nch) { STAGE(c + 2, 0); LOADX(c + 2, xa); }
    COMPUTE(xb, 1);
    __syncthreads();
    FOLD();
  }

  if (gridDim.y != 1) {
    // ---- partial mode: write (hi, lo) planes ----
#pragma unroll
    for (int n = 0; n < 4; ++n)
#pragma unroll
      for (int r = 0; r < 4; ++r) {
        const int t = t0 + wid * 16 + lq * 4 + r;
        const size_t o = ((size_t)by * T + t) * E_DIM + n * 16 + lc;
        hi_p[o] = sum_[n][r];
        lo_p[o] = comp[n][r] + acc_c[n][r];
      }
    return;
  }

  // ---- fused epilogue (fallback, gridDim.y==1) ----
  float bias_v[4];
#pragma unroll
  for (int n = 0; n < 4; ++n) bias_v[n] = bias[n * 16 + lc];

  float pr[4][4], bi[4][4];
#pragma unroll
  for (int n = 0; n < 4; ++n)
#pragma unroll
    for (int r = 0; r < 4; ++r) {
      float logit = sum_[n][r] + (comp[n][r] + acc_c[n][r]);
      float p = 1.0f / (1.0f + expf(-logit));
      pr[n][r] = p;
      bi[n][r] = p + bias_v[n];
    }

#pragma unroll
  for (int r = 0; r < 4; ++r) {
    float v0 = bi[0][r], v1 = bi[1][r], v2 = bi[2][r], v3 = bi[3][r];
    float p0 = pr[0][r], p1 = pr[1][r], p2 = pr[2][r], p3 = pr[3][r];
    float sum = 0.f, selp = 0.f;
    int seli = 0;
#pragma unroll
    for (int k = 0; k < 8; ++k) {
      float bv = v0; int bn = 0; float bp = p0;
      if (v1 > bv) { bv = v1; bn = 1; bp = p1; }
      if (v2 > bv) { bv = v2; bn = 2; bp = p2; }
      if (v3 > bv) { bv = v3; bn = 3; bp = p3; }
      int be = bn * 16 + lc;
#pragma unroll
      for (int off = 8; off >= 1; off >>= 1) {
        float ov = __shfl_xor(bv, off);
        float op = __shfl_xor(bp, off);
        int   oe = __shfl_xor(be, off);
        if (ov > bv || (ov == bv && oe < be)) { bv = ov; bp = op; be = oe; }
      }
      sum += bp;
      if (lc == k) { selp = bp; seli = be; }
      if (lc == (be & 15)) {
        int gsel = be >> 4;
        if      (gsel == 0) v0 = -1e30f;
        else if (gsel == 1) v1 = -1e30f;
        else if (gsel == 2) v2 = -1e30f;
        else                v3 = -1e30f;
      }
    }
    if (lc < 8) {
      const int t = t0 + wid * 16 + lq * 4 + r;
      outw[(size_t)t * 8 + lc] = selp * 2.5f / (sum + 1e-20f);
      outi[(size_t)t * 8 + lc] = (float)seli;
    }
  }
}

// ---- kernel T: combine partials (TwoSum) + sigmoid + top-8 ----
__global__ __launch_bounds__(256) void router_topk(
    const float* __restrict__ hi_p, const float* __restrict__ lo_p,
    const float* __restrict__ bias, float* __restrict__ outw,
    float* __restrict__ outi, int T)
{
  const int lane = threadIdx.x & 63;
  const int t = blockIdx.x * 4 + (threadIdx.x >> 6);
  if (t >= T) return;

  float s = 0.f, c = 0.f, losum = 0.f;
#pragma unroll
  for (int p = 0; p < NPART; ++p) {
    const size_t o = ((size_t)p * T + t) * E_DIM + lane;
    float a = hi_p[o];
    float tt = s + a;
    float z = tt - s;
    c += (s - (tt - z)) + (a - z);
    s = tt;
    losum += lo_p[o];
  }
  const float logit = s + (c + losum);

  const float prob = 1.0f / (1.0f + expf(-logit));
  float v = prob + bias[lane];

  float sum = 0.f, selw = 0.f;
  int seli = 0;
#pragma unroll
  for (int k = 0; k < 8; ++k) {
    float rv = v;
    int   ri = lane;
#pragma unroll
    for (int off = 32; off > 0; off >>= 1) {
      float ov = __shfl_xor(rv, off);
      int   oi = __shfl_xor(ri, off);
      if (ov > rv || (ov == rv && oi < ri)) { rv = ov; ri = oi; }
    }
    float pwin = __shfl(prob, ri);
    sum += pwin;
    if (lane == k)  { selw = pwin; seli = ri; }
    if (lane == ri) v = -INFINITY;
  }

  if (lane < 8) {
    float scale = 2.5f / (sum + 1e-20f);
    outw[(size_t)t * 8 + lane] = selw * scale;
    outi[(size_t)t * 8 + lane] = (float)seli;
  }
}

extern "C" void kernel_launch(void* const* d_in, const int* in_sizes, int n_in,
                              void* d_out, int out_size, void* d_ws, size_t ws_size,
                              hipStream_t stream) {
  const float* x    = (const float*)d_in[0];
  const float* w    = (const float*)d_in[1];
  const float* bias = (const float*)d_in[2];

  const int E    = in_sizes[2];          // 64
  const int Hdim = in_sizes[1] / E;      // 4096
  const int T    = in_sizes[0] / Hdim;   // 16384

  unsigned char* ws = (unsigned char*)d_ws;
  unsigned char* w3 = ws + W3_OFF;             // 1.5 MB
  float* hi_p = (float*)(ws + HI_OFF);         // NPART*T*64 f32 = 16 MB
  float* lo_p = hi_p + (size_t)NPART * T * E_DIM;

  const size_t need = (size_t)HI_OFF + (size_t)2 * NPART * T * E_DIM * sizeof(float);
  const int nparts = (ws_size >= need) ? NPART : 1;

  const int nElemGroups = E * Hdim / 16;
  split_w<<<(nElemGroups + 255) / 256, 256, 0, stream>>>(w, w3, Hdim);

  float* outw = (float*)d_out;
  float* outi = outw + (size_t)T * 8;

  dim3 gridG(T / 64, nparts);
  router_mfma<<<gridG, 256, 0, stream>>>(x, w3, bias, outw, outi, hi_p, lo_p, T, Hdim);

  if (nparts != 1) {
    router_topk<<<(T + 3) / 4, 256, 0, stream>>>(hi_p, lo_p, bias, outw, outi, T);
  }
}